// Round 7
// baseline (291.150 us; speedup 1.0000x reference)
//
#include <hip/hip_runtime.h>

// Net_3152505995417: tiny GNN forward (N=116, E=6670, HID=64, EDIM=5).
// Algebraic collapses (exact, absmax=0 since R1):
//  * node_conv: out = D @ (Hv@W) + b, D[i,j] = d[eid(i,j)] off-diag (symmetric).
//  * edge_conv: out[e=(a,b),k] = dv[a]*(S[a,k]-Gp[e,k]) + dv[b]*(S[b,k]-Gp[e,k]) + be,
//      Gp[f] = G[f]/(max(dv[c],dv[d],0)+eps), S[i] = sum_{f∋i} Gp[f].
// R7: SINGLE WORKGROUP (1 block x 1024 threads, one CU). R3-R6 falsified every
//   multi-block barrier theory; the 29-block topology pays die-crossings on
//   every hop. Total work ~3.6M FMA = ~12us VALU floor on one CU. All sync is
//   __syncthreads(); intra-workgroup global coherence needs no fences/scopes.
//   Structure: D1/D2 as DENSE [116][116] fp32 in LDS (uniform b128 quad reads,
//   zeroed diagonal = free j==i masking); G[7][5] per-thread in registers
//   (edge-range ownership, never in memory); X/x2/Y1/Y2 via global ws (same-CU
//   L2). LDS 57.7KB. One dispatch, no memset.

#define NN   116
#define ND   (NN*NN)    // 13456
#define EE   6670
#define HID  64
#define EDIM 5
#define OUTD 4
#define ENC  122
#define EPSF 1e-10f
#define NQ   29         // 116/4 column quads
#define EPT  7          // edges per thread (1024*7 >= 6670)

__global__ __launch_bounds__(1024) void fused(
    const float* __restrict__ enc, const float* __restrict__ ea,
    const int* __restrict__ eidx,
    const float* __restrict__ W_enc, const float* __restrict__ b_enc,
    const float* __restrict__ W1, const float* __restrict__ b1,
    const float* __restrict__ p1, const float* __restrict__ We,
    const float* __restrict__ be, const float* __restrict__ pe,
    const float* __restrict__ W2, const float* __restrict__ b2,
    const float* __restrict__ p2, const float* __restrict__ Wl,
    const float* __restrict__ bl,
    float* __restrict__ Xg, float* __restrict__ Yg,
    float* __restrict__ out)
{
    __shared__ __align__(16) float sD[ND];   // dense D1, then dense D2 (53.8 KB)
    __shared__ float sM[960];                // [0:580] sS, [580:696] sDV; later pool[15*64]

    const int tid  = threadIdx.x;
    const int w    = tid >> 6, lane = tid & 63;
    const int i0   = w * 8;                  // node group base; waves 0..14 own nodes
    int ic[8];
    #pragma unroll
    for (int j = 0; j < 8; ++j) ic[j] = min(i0 + j, NN - 1);   // clamped (guard stores)

    // ---- S0: zero dense-D (incl. diagonal -> free j==i masking) and sS.
    for (int u = tid; u < ND; u += 1024) sD[u] = 0.f;
    for (int u = tid; u < NN*EDIM; u += 1024) sM[u] = 0.f;

    // ---- S1: X = enc @ W_enc + b_enc  -> Xg.  8 nodes/wave, quad-k, float2 enc reads.
    {
        float bv = b_enc[lane];
        float xa[8];
        #pragma unroll
        for (int j = 0; j < 8; ++j) xa[j] = bv;
        for (int q = 0; q < 30; ++q) {
            const int k = 4*q;
            float w0 = W_enc[(k+0)*HID + lane], w1 = W_enc[(k+1)*HID + lane];
            float w2 = W_enc[(k+2)*HID + lane], w3 = W_enc[(k+3)*HID + lane];
            #pragma unroll
            for (int j = 0; j < 8; ++j) {
                const float* er = enc + ic[j]*ENC + k;          // 8B-aligned
                float2 p01 = *(const float2*)(er);
                float2 p23 = *(const float2*)(er + 2);
                xa[j] = fmaf(p01.x, w0, fmaf(p01.y, w1, fmaf(p23.x, w2, fmaf(p23.y, w3, xa[j]))));
            }
        }
        {   // tail k = 120, 121
            float w0 = W_enc[120*HID + lane], w1 = W_enc[121*HID + lane];
            #pragma unroll
            for (int j = 0; j < 8; ++j) {
                float2 p01 = *(const float2*)(enc + ic[j]*ENC + 120);
                xa[j] = fmaf(p01.x, w0, fmaf(p01.y, w1, xa[j]));
            }
        }
        #pragma unroll
        for (int j = 0; j < 8; ++j)
            if (i0 + j < NN) Xg[(i0 + j)*HID + lane] = xa[j];
    }
    __syncthreads();   // #1: Xg visible (same-CU L2)

    // ---- S2: Y1 = X @ W1 -> Yg.  Uniform float4 X reads (broadcast), coalesced W1.
    {
        float ya[8] = {0.f,0.f,0.f,0.f,0.f,0.f,0.f,0.f};
        for (int q = 0; q < 16; ++q) {
            const int k = 4*q;
            float w0 = W1[(k+0)*HID + lane], w1 = W1[(k+1)*HID + lane];
            float w2 = W1[(k+2)*HID + lane], w3 = W1[(k+3)*HID + lane];
            #pragma unroll
            for (int j = 0; j < 8; ++j) {
                float4 xq = *(const float4*)(Xg + ic[j]*HID + k);   // 16B-aligned, uniform
                ya[j] = fmaf(xq.x, w0, fmaf(xq.y, w1, fmaf(xq.z, w2, fmaf(xq.w, w3, ya[j]))));
            }
        }
        #pragma unroll
        for (int j = 0; j < 8; ++j)
            if (i0 + j < NN) Yg[(i0 + j)*HID + lane] = ya[j];
    }
    __syncthreads();   // #2

    // ---- S3: per-thread edges [tid*7, tid*7+7): d1 -> dense sD (2 scattered writes),
    //          G[r][k] = relu(ea)@We kept in REGISTERS. Also (a,b) packed.
    float G[EPT][EDIM];
    int   eab[EPT];
    {
        float p1r[EDIM], Wer[EDIM*EDIM];
        #pragma unroll
        for (int k = 0; k < EDIM; ++k) p1r[k] = p1[k];
        #pragma unroll
        for (int u = 0; u < EDIM*EDIM; ++u) Wer[u] = We[u];
        #pragma unroll
        for (int r = 0; r < EPT; ++r) {
            const int e = tid*EPT + r;
            if (e < EE) {
                const int a = eidx[e], b = eidx[EE + e];
                eab[r] = (a << 16) | b;
                const float* rr = ea + e*EDIM;
                float e0 = rr[0], e1 = rr[1], e2 = rr[2], e3 = rr[3], e4 = rr[4];
                float d1 = e0*p1r[0] + e1*p1r[1] + e2*p1r[2] + e3*p1r[3] + e4*p1r[4];
                sD[a*NN + b] = d1;
                sD[b*NN + a] = d1;
                float q0 = fmaxf(e0,0.f), q1 = fmaxf(e1,0.f), q2 = fmaxf(e2,0.f),
                      q3 = fmaxf(e3,0.f), q4 = fmaxf(e4,0.f);
                #pragma unroll
                for (int k = 0; k < EDIM; ++k)
                    G[r][k] = q0*Wer[k] + q1*Wer[5+k] + q2*Wer[10+k] + q3*Wer[15+k] + q4*Wer[20+k];
            } else {
                eab[r] = -1;
                #pragma unroll
                for (int k = 0; k < EDIM; ++k) G[r][k] = 0.f;
            }
        }
    }
    __syncthreads();   // #3: dense D1 + Yg ready

    // ---- S4: x2 = relu(D1 @ Y1 + b1) -> Xg; dv -> sDV.  D1 via uniform b128 quads.
    {
        float b1v = b1[lane];
        float xb[8];
        #pragma unroll
        for (int j = 0; j < 8; ++j) xb[j] = b1v;
        for (int J = 0; J < NQ; ++J) {
            const int j4 = 4*J;
            float y0 = Yg[(j4+0)*HID + lane], y1 = Yg[(j4+1)*HID + lane];
            float y2 = Yg[(j4+2)*HID + lane], y3 = Yg[(j4+3)*HID + lane];
            #pragma unroll
            for (int j = 0; j < 8; ++j) {
                float4 dq = *(const float4*)(sD + ic[j]*NN + j4);   // 16B-aligned, uniform
                xb[j] = fmaf(dq.x, y0, fmaf(dq.y, y1, fmaf(dq.z, y2, fmaf(dq.w, y3, xb[j]))));
            }
        }
        float pel = pe[lane];
        #pragma unroll
        for (int j = 0; j < 8; ++j) {
            float v = fmaxf(xb[j], 0.f);
            xb[j] = v;
            float r = v * pel;
            #pragma unroll
            for (int off = 32; off > 0; off >>= 1) r += __shfl_xor(r, off, 64);
            if (lane == 0 && i0 + j < NN) sM[580 + i0 + j] = r;    // dv
        }
        #pragma unroll
        for (int j = 0; j < 8; ++j)
            if (i0 + j < NN) Xg[(i0 + j)*HID + lane] = xb[j];      // x2 over X
    }
    __syncthreads();   // #4: x2, dv ready

    // ---- S5: Y2 = x2 @ W2 -> Yg; and stage C: sS[i,k] += G*rc (LDS atomics).
    {
        float yb[8] = {0.f,0.f,0.f,0.f,0.f,0.f,0.f,0.f};
        for (int q = 0; q < 16; ++q) {
            const int k = 4*q;
            float w0 = W2[(k+0)*HID + lane], w1 = W2[(k+1)*HID + lane];
            float w2 = W2[(k+2)*HID + lane], w3 = W2[(k+3)*HID + lane];
            #pragma unroll
            for (int j = 0; j < 8; ++j) {
                float4 xq = *(const float4*)(Xg + ic[j]*HID + k);
                yb[j] = fmaf(xq.x, w0, fmaf(xq.y, w1, fmaf(xq.z, w2, fmaf(xq.w, w3, yb[j]))));
            }
        }
        #pragma unroll
        for (int j = 0; j < 8; ++j)
            if (i0 + j < NN) Yg[(i0 + j)*HID + lane] = yb[j];

        #pragma unroll
        for (int r = 0; r < EPT; ++r) {
            if (eab[r] >= 0) {
                const int a = eab[r] >> 16, b = eab[r] & 0xffff;
                float da = sM[580 + a], db = sM[580 + b];
                float rc = 1.f / (fmaxf(fmaxf(da, db), 0.f) + EPSF);
                #pragma unroll
                for (int k = 0; k < EDIM; ++k) {
                    float h = G[r][k] * rc;
                    atomicAdd(&sM[a*EDIM + k], h);
                    atomicAdd(&sM[b*EDIM + k], h);
                }
            }
        }
    }
    __syncthreads();   // #5: sS, Y2 ready

    // ---- S7: d2 per edge -> dense sD (overwrites D1 off-diag; diag stays 0).
    {
        float ber[EDIM], p2r[EDIM];
        #pragma unroll
        for (int k = 0; k < EDIM; ++k) { ber[k] = be[k]; p2r[k] = p2[k]; }
        #pragma unroll
        for (int r = 0; r < EPT; ++r) {
            if (eab[r] >= 0) {
                const int a = eab[r] >> 16, b = eab[r] & 0xffff;
                float da = sM[580 + a], db = sM[580 + b];
                float rc = 1.f / (fmaxf(fmaxf(da, db), 0.f) + EPSF);
                float acc = 0.f;
                #pragma unroll
                for (int k = 0; k < EDIM; ++k) {
                    float gp = G[r][k] * rc;
                    float v = fmaf(da, sM[a*EDIM + k] - gp,
                              fmaf(db, sM[b*EDIM + k] - gp, ber[k]));
                    acc = fmaf(fmaxf(v, 0.f), p2r[k], acc);
                }
                sD[a*NN + b] = acc;
                sD[b*NN + a] = acc;
            }
        }
    }
    __syncthreads();   // #6: dense D2 ready

    // ---- S8: x3 = D2 @ Y2 + b2; per-wave pool partial -> sM[w*64+lane].
    {
        float b2v = b2[lane];
        float xc[8];
        #pragma unroll
        for (int j = 0; j < 8; ++j) xc[j] = b2v;
        for (int J = 0; J < NQ; ++J) {
            const int j4 = 4*J;
            float y0 = Yg[(j4+0)*HID + lane], y1 = Yg[(j4+1)*HID + lane];
            float y2 = Yg[(j4+2)*HID + lane], y3 = Yg[(j4+3)*HID + lane];
            #pragma unroll
            for (int j = 0; j < 8; ++j) {
                float4 dq = *(const float4*)(sD + ic[j]*NN + j4);
                xc[j] = fmaf(dq.x, y0, fmaf(dq.y, y1, fmaf(dq.z, y2, fmaf(dq.w, y3, xc[j]))));
            }
        }
        float p = 0.f;
        #pragma unroll
        for (int j = 0; j < 8; ++j)
            if (i0 + j < NN) p += xc[j];
        if (w < 15) sM[w*64 + lane] = p;     // overlays sS/sDV (dead after S7)
    }
    __syncthreads();   // #7

    // ---- S9: out = (pool/N) @ Wl + bl  (wave 0).
    if (w == 0) {
        float val = 0.f;
        #pragma unroll
        for (int ww = 0; ww < 15; ++ww) val += sM[ww*64 + lane];
        val *= (1.0f / NN);
        float res[OUTD];
        #pragma unroll
        for (int o = 0; o < OUTD; ++o) {
            float r = val * Wl[lane*OUTD + o];
            #pragma unroll
            for (int off = 32; off > 0; off >>= 1) r += __shfl_xor(r, off, 64);
            res[o] = r;
        }
        if (lane < OUTD) out[lane] = res[lane] + bl[lane];
    }
}

extern "C" void kernel_launch(void* const* d_in, const int* in_sizes, int n_in,
                              void* d_out, int out_size, void* d_ws, size_t ws_size,
                              hipStream_t stream)
{
    const float* enc   = (const float*)d_in[0];
    const float* ea    = (const float*)d_in[1];
    const int*   eidx  = (const int*)  d_in[2];
    const float* W_enc = (const float*)d_in[3];
    const float* b_enc = (const float*)d_in[4];
    const float* W1    = (const float*)d_in[5];
    const float* b1    = (const float*)d_in[6];
    const float* p1    = (const float*)d_in[7];
    const float* We    = (const float*)d_in[8];
    const float* be    = (const float*)d_in[9];
    const float* pe    = (const float*)d_in[10];
    const float* W2    = (const float*)d_in[11];
    const float* b2    = (const float*)d_in[12];
    const float* p2    = (const float*)d_in[13];
    const float* Wl    = (const float*)d_in[14];
    const float* bl    = (const float*)d_in[15];
    float* ws = (float*)d_ws;

    float* Xg = ws;            // [NN*HID] X, then x2
    float* Yg = ws + NN*HID;   // [NN*HID] Y1, then Y2
    float* out = (float*)d_out;

    fused<<<1, 1024, 0, stream>>>(enc, ea, eidx, W_enc, b_enc, W1, b1, p1, We,
                                  be, pe, W2, b2, p2, Wl, bl, Xg, Yg, out);
}